// Round 1
// baseline (259.191 us; speedup 1.0000x reference)
//
#include <hip/hip_runtime.h>
#include <hip/hip_bf16.h>

#define Bn   4096
#define Sn   128
#define En   768
#define HIDn 384
#define NHn  9
#define NEn  5
#define NCOL 5376    // NH*HID + NE*HID
#define GHOFF 3456   // NH*HID

typedef __attribute__((ext_vector_type(8))) short short8;
typedef __attribute__((ext_vector_type(4))) float f32x4;

__device__ __forceinline__ unsigned short f2bf(float v) {
  unsigned int x = __float_as_uint(v);
  x += 0x7fffu + ((x >> 16) & 1u);   // RNE
  return (unsigned short)(x >> 16);
}

__device__ __forceinline__ float dot4(float4 a, float4 b) {
  return fmaf(a.x, b.x, fmaf(a.y, b.y, fmaf(a.z, b.z, a.w * b.w)));
}
__device__ __forceinline__ void fma4(float4& p, float w, float4 v) {
  p.x = fmaf(w, v.x, p.x); p.y = fmaf(w, v.y, p.y);
  p.z = fmaf(w, v.z, p.z); p.w = fmaf(w, v.w, p.w);
}

// ---------------- K1: fused mask + softmax + pool. 1 wave/sample. ----------
__global__ __launch_bounds__(256) void pool_kernel(
    const float* __restrict__ feature, const int* __restrict__ masks,
    const float* __restrict__ attn_w, unsigned short* __restrict__ pooled) {
  const int lane = threadIdx.x & 63;
  const int b = blockIdx.x * 4 + (threadIdx.x >> 6);
  const float4* aw = (const float4*)attn_w;
  const float4 aw0 = aw[lane], aw1 = aw[64 + lane], aw2 = aw[128 + lane];
  const float4* f = (const float4*)(feature + (size_t)b * (Sn * En));
  const int* mrow = masks + b * Sn;
  unsigned long long bm0 = __ballot(mrow[lane] != 0);
  unsigned long long bm1 = __ballot(mrow[64 + lane] != 0);
  float4 p0 = {0,0,0,0}, p1 = {0,0,0,0}, p2 = {0,0,0,0};
  float lsum = 0.f;
  for (int s = 0; s < Sn; ++s) {
    bool on = (s < 64) ? ((bm0 >> s) & 1ull) : ((bm1 >> (s - 64)) & 1ull);
    if (!on) continue;                       // masked row: alpha == 0 exactly
    const float4* row = f + s * (En / 4);
    float4 f0 = row[lane], f1 = row[64 + lane], f2 = row[128 + lane];
    float part = dot4(f0, aw0) + dot4(f1, aw1) + dot4(f2, aw2);
    #pragma unroll
    for (int off = 32; off; off >>= 1) part += __shfl_xor(part, off);
    float w = __expf(part);                  // |score| <~ 4 -> safe without max
    lsum += w;
    fma4(p0, w, f0); fma4(p1, w, f1); fma4(p2, w, f2);
  }
  if (lsum == 0.f) {                         // all-masked: uniform alpha
    for (int s = 0; s < Sn; ++s) {
      const float4* row = f + s * (En / 4);
      fma4(p0, 1.f, row[lane]); fma4(p1, 1.f, row[64 + lane]); fma4(p2, 1.f, row[128 + lane]);
    }
    lsum = (float)Sn;
  }
  const float inv = 1.f / lsum;
  const size_t base = (size_t)b * (En / 4);
  ushort4 u;
  u.x = f2bf(p0.x * inv); u.y = f2bf(p0.y * inv); u.z = f2bf(p0.z * inv); u.w = f2bf(p0.w * inv);
  ((ushort4*)pooled)[base + lane] = u;
  u.x = f2bf(p1.x * inv); u.y = f2bf(p1.y * inv); u.z = f2bf(p1.z * inv); u.w = f2bf(p1.w * inv);
  ((ushort4*)pooled)[base + 64 + lane] = u;
  u.x = f2bf(p2.x * inv); u.y = f2bf(p2.y * inv); u.z = f2bf(p2.z * inv); u.w = f2bf(p2.w * inv);
  ((ushort4*)pooled)[base + 128 + lane] = u;
}

// ------------- K2a: pack [gate_w1 | expert_w] into MFMA B-fragment layout ---
// Bp[(nt*24 + kt)*512 + lane*8 + e] = W[kt*32 + (lane>>4)*8 + e][nt*16 + (lane&15)]
__global__ __launch_bounds__(256) void pack_kernel(
    const float* __restrict__ g1, const float* __restrict__ ew,
    unsigned short* __restrict__ Bp) {
  const int lane = threadIdx.x & 63;
  const int pair = blockIdx.x * 4 + (threadIdx.x >> 6); // == nt*24 + kt
  const int nt = pair / 24, kt = pair % 24;
  const int q = lane >> 4, j = lane & 15;
  const int n = nt * 16 + j;
  const float* src;
  if (n < GHOFF) src = g1 + (size_t)(n / HIDn) * (En * HIDn) + (n % HIDn);
  else { int m = n - GHOFF; src = ew + (size_t)(m / HIDn) * (En * HIDn) + (m % HIDn); }
  unsigned short out[8] __attribute__((aligned(16)));
  #pragma unroll
  for (int e = 0; e < 8; ++e) {
    int k = kt * 32 + q * 8 + e;
    out[e] = f2bf(src[(size_t)k * HIDn]);
  }
  *(uint4*)&Bp[(size_t)pair * 512 + lane * 8] = *(const uint4*)out;
}

// ------------- K2b: column bias vector [gate_b1 | expert_b] ----------------
__global__ void bias_kernel(const float* __restrict__ gb1, const float* __restrict__ eb,
                            float* __restrict__ bias) {
  int n = blockIdx.x * 256 + threadIdx.x;
  if (n >= NCOL) return;
  bias[n] = (n < GHOFF) ? gb1[n] : eb[n - GHOFF];
}

// ------------- K3: C = relu(A @ W + bias), A[4096,768]bf16, C[4096,5376]f32 -
__global__ __launch_bounds__(256) void gemm_kernel(
    const unsigned short* __restrict__ A, const unsigned short* __restrict__ Bp,
    const float* __restrict__ bias, float* __restrict__ C) {
  __shared__ unsigned short Alds[128 * 40];   // rows padded 32->40 elems
  __shared__ unsigned short Blds[8 * 512];    // 8 n-tiles, fragment-order
  const int t = threadIdx.x, lane = t & 63, wid = t >> 6;
  const int wm = wid >> 1, wn = wid & 1;
  const int m0 = blockIdx.y * 128, n0 = blockIdx.x * 128;
  const int ntg0 = blockIdx.x * 8;
  f32x4 acc[4][4] = {};
  const int r = t >> 2, c0 = (t & 3) * 8;
  for (int kt = 0; kt < 24; ++kt) {
    __syncthreads();
    *(uint4*)&Alds[r * 40 + c0] =
        *(const uint4*)&A[(size_t)(m0 + r) * En + kt * 32 + c0];
    *(uint4*)&Alds[(r + 64) * 40 + c0] =
        *(const uint4*)&A[(size_t)(m0 + r + 64) * En + kt * 32 + c0];
    #pragma unroll
    for (int rnd = 0; rnd < 2; ++rnd) {
      int chunk = t + rnd * 256;
      int nt = chunk >> 6, l2 = chunk & 63;
      *(uint4*)&Blds[nt * 512 + l2 * 8] =
          *(const uint4*)&Bp[((size_t)(ntg0 + nt) * 24 + kt) * 512 + l2 * 8];
    }
    __syncthreads();
    short8 af[4], bfv[4];
    const int arow = wm * 64 + (lane & 15);
    const int aq = (lane >> 4) * 8;
    #pragma unroll
    for (int i = 0; i < 4; ++i)
      af[i] = *(const short8*)&Alds[(arow + i * 16) * 40 + aq];
    #pragma unroll
    for (int i = 0; i < 4; ++i)
      bfv[i] = *(const short8*)&Blds[(wn * 4 + i) * 512 + lane * 8];
    #pragma unroll
    for (int i = 0; i < 4; ++i)
      #pragma unroll
      for (int jj = 0; jj < 4; ++jj)
        acc[i][jj] = __builtin_amdgcn_mfma_f32_16x16x32_bf16(af[i], bfv[jj], acc[i][jj], 0, 0, 0);
  }
  // C/D layout (verified): col = lane&15, row = (lane>>4)*4 + reg
  const int rbase = m0 + wm * 64 + ((lane >> 4) << 2);
  const int cbase = n0 + wn * 64 + (lane & 15);
  #pragma unroll
  for (int i = 0; i < 4; ++i)
    #pragma unroll
    for (int jj = 0; jj < 4; ++jj) {
      int col = cbase + jj * 16;
      float bv = bias[col];
      #pragma unroll
      for (int rr = 0; rr < 4; ++rr) {
        float v = acc[i][jj][rr] + bv;
        C[(size_t)(rbase + i * 16 + rr) * NCOL + col] = v > 0.f ? v : 0.f;
      }
    }
}

// ------------- K4: per-sample gate softmax + expert combine + head ---------
__global__ __launch_bounds__(256) void tail_kernel(
    const float* __restrict__ C, const int* __restrict__ category,
    const float* __restrict__ g2, const float* __restrict__ gb2,
    const float* __restrict__ hw, const float* __restrict__ hb,
    float* __restrict__ out) {
  const int lane = threadIdx.x & 63;
  const int b = blockIdx.x * 4 + (threadIdx.x >> 6);
  const int cat = category[b];
  const float* crow = C + (size_t)b * NCOL;
  float gh[6], hv[6];
  #pragma unroll
  for (int j = 0; j < 6; ++j) {
    int o = lane + 64 * j;
    gh[j] = crow[cat * HIDn + o];    // relu(pooled@W1[cat]+b1) from GEMM
    hv[j] = hw[cat * HIDn + o];
  }
  float g[5];
  #pragma unroll
  for (int k = 0; k < 5; ++k) {
    float p = 0.f;
    #pragma unroll
    for (int j = 0; j < 6; ++j) {
      int o = lane + 64 * j;
      p = fmaf(gh[j], g2[(size_t)(cat * HIDn + o) * 5 + k], p);
    }
    #pragma unroll
    for (int off = 32; off; off >>= 1) p += __shfl_xor(p, off);
    g[k] = p + gb2[cat * 5 + k];
  }
  float mx = g[0];
  #pragma unroll
  for (int k = 1; k < 5; ++k) mx = fmaxf(mx, g[k]);
  float gs = 0.f;
  #pragma unroll
  for (int k = 0; k < 5; ++k) { g[k] = __expf(g[k] - mx); gs += g[k]; }
  const float ginv = 1.f / gs;
  float sacc = 0.f;
  #pragma unroll
  for (int k = 0; k < 5; ++k) {
    float p = 0.f;
    #pragma unroll
    for (int j = 0; j < 6; ++j) {
      int o = lane + 64 * j;
      p = fmaf(crow[GHOFF + k * HIDn + o], hv[j], p);   // relu'd expert hidden
    }
    sacc = fmaf(g[k] * ginv, p, sacc);
  }
  #pragma unroll
  for (int off = 32; off; off >>= 1) sacc += __shfl_xor(sacc, off);
  if (lane == 0) {
    float logit = sacc + hb[cat];
    out[b] = 1.f / (1.f + __expf(-logit));
  }
}

extern "C" void kernel_launch(void* const* d_in, const int* in_sizes, int n_in,
                              void* d_out, int out_size, void* d_ws, size_t ws_size,
                              hipStream_t stream) {
  const float* feature  = (const float*)d_in[0];
  const int*   masks    = (const int*)d_in[1];
  const int*   category = (const int*)d_in[2];
  const float* attn_w   = (const float*)d_in[3];
  // d_in[4] attn_b: cancels in softmax, unused
  const float* gate_w1  = (const float*)d_in[5];
  const float* gate_b1  = (const float*)d_in[6];
  const float* gate_w2  = (const float*)d_in[7];
  const float* gate_b2  = (const float*)d_in[8];
  const float* expert_w = (const float*)d_in[9];
  const float* expert_b = (const float*)d_in[10];
  const float* head_w   = (const float*)d_in[11];
  const float* head_b   = (const float*)d_in[12];
  float* out = (float*)d_out;

  char* ws = (char*)d_ws;
  unsigned short* pooled = (unsigned short*)ws;              // 4096*768*2  = 6,291,456 B
  unsigned short* Bp     = (unsigned short*)(ws + 6291456);  // 336*24*512*2= 8,257,536 B
  float* bias            = (float*)(ws + 14548992);          // 5376*4      =    21,504 B
  float* Cbuf            = (float*)(ws + 14570496);          // 4096*5376*4 = 88,080,384 B

  pool_kernel<<<dim3(1024), dim3(256), 0, stream>>>(feature, masks, attn_w, pooled);
  pack_kernel<<<dim3(2016), dim3(256), 0, stream>>>(gate_w1, expert_w, Bp);
  bias_kernel<<<dim3(21), dim3(256), 0, stream>>>(gate_b1, expert_b, bias);
  gemm_kernel<<<dim3(42, 32), dim3(256), 0, stream>>>(pooled, Bp, bias, Cbuf);
  tail_kernel<<<dim3(1024), dim3(256), 0, stream>>>(Cbuf, category, gate_w2, gate_b2, head_w, head_b, out);
}

// Round 2
// 236.598 us; speedup vs baseline: 1.0955x; 1.0955x over previous
//
#include <hip/hip_runtime.h>
#include <hip/hip_bf16.h>

#define Bn   4096
#define Sn   128
#define En   768
#define HIDn 384
#define NHn  9
#define NEn  5
#define NECOL 1920        // NE*HID expert columns
#define MAXTILES 41       // max padded m-tiles: floor(4096/128)+9
#define PADROWS (MAXTILES*128)

typedef __attribute__((ext_vector_type(8))) short short8;
typedef __attribute__((ext_vector_type(4))) float f32x4;

__device__ __forceinline__ unsigned short f2bf(float v) {
  unsigned int x = __float_as_uint(v);
  x += 0x7fffu + ((x >> 16) & 1u);   // RNE
  return (unsigned short)(x >> 16);
}
__device__ __forceinline__ float dot4(float4 a, float4 b) {
  return fmaf(a.x, b.x, fmaf(a.y, b.y, fmaf(a.z, b.z, a.w * b.w)));
}
__device__ __forceinline__ void fma4(float4& p, float w, float4 v) {
  p.x = fmaf(w, v.x, p.x); p.y = fmaf(w, v.y, p.y);
  p.z = fmaf(w, v.z, p.z); p.w = fmaf(w, v.w, p.w);
}

// ---------------- K1: fused mask+softmax+pool. 1 block/sample, 4 waves. ----
__global__ __launch_bounds__(256) void pool_kernel(
    const float* __restrict__ feature, const int* __restrict__ masks,
    const float* __restrict__ attn_w, unsigned short* __restrict__ pooled) {
  __shared__ __align__(16) float pbuf[4][768];
  __shared__ float sbuf[4];
  const int t = threadIdx.x, lane = t & 63, wid = t >> 6;
  const int b = blockIdx.x;
  const float4* aw = (const float4*)attn_w;
  const float4 aw0 = aw[lane], aw1 = aw[64 + lane], aw2 = aw[128 + lane];
  const float4* fb = (const float4*)(feature + (size_t)b * (Sn * En));
  // wave wid owns rows [wid*32, wid*32+32)
  unsigned long long bal = __ballot(lane < 32 && masks[b * Sn + wid * 32 + (lane & 31)] != 0);
  unsigned int m = (unsigned int)bal;
  float4 p0 = {0,0,0,0}, p1 = {0,0,0,0}, p2 = {0,0,0,0};
  float lsum = 0.f;
  if (m) {
    int s = __builtin_ctz(m); m &= m - 1;
    const float4* rp = fb + (wid * 32 + s) * (En / 4);
    float4 c0 = rp[lane], c1 = rp[64 + lane], c2 = rp[128 + lane];
    while (m) {
      int s2 = __builtin_ctz(m); m &= m - 1;
      const float4* rp2 = fb + (wid * 32 + s2) * (En / 4);
      float4 n0 = rp2[lane], n1 = rp2[64 + lane], n2 = rp2[128 + lane];
      float part = dot4(c0, aw0) + dot4(c1, aw1) + dot4(c2, aw2);
      #pragma unroll
      for (int off = 32; off; off >>= 1) part += __shfl_xor(part, off);
      float w = __expf(part);              // |score| small -> no max-sub needed
      lsum += w;
      fma4(p0, w, c0); fma4(p1, w, c1); fma4(p2, w, c2);
      c0 = n0; c1 = n1; c2 = n2;
    }
    float part = dot4(c0, aw0) + dot4(c1, aw1) + dot4(c2, aw2);
    #pragma unroll
    for (int off = 32; off; off >>= 1) part += __shfl_xor(part, off);
    float w = __expf(part);
    lsum += w;
    fma4(p0, w, c0); fma4(p1, w, c1); fma4(p2, w, c2);
  }
  ((float4*)pbuf[wid])[lane] = p0;
  ((float4*)pbuf[wid])[64 + lane] = p1;
  ((float4*)pbuf[wid])[128 + lane] = p2;
  if (lane == 0) sbuf[wid] = lsum;
  __syncthreads();
  float total = sbuf[0] + sbuf[1] + sbuf[2] + sbuf[3];
  if (total == 0.f) {                      // all rows masked: uniform alpha
    p0 = p1 = p2 = float4{0,0,0,0};
    for (int s = 0; s < 32; ++s) {
      const float4* rp = fb + (wid * 32 + s) * (En / 4);
      fma4(p0, 1.f, rp[lane]); fma4(p1, 1.f, rp[64 + lane]); fma4(p2, 1.f, rp[128 + lane]);
    }
    ((float4*)pbuf[wid])[lane] = p0;
    ((float4*)pbuf[wid])[64 + lane] = p1;
    ((float4*)pbuf[wid])[128 + lane] = p2;
    __syncthreads();
    total = 128.f;
  }
  const float inv = 1.f / total;
  if (t < 192) {
    float4 s0 = ((const float4*)pbuf[0])[t];
    float4 s1 = ((const float4*)pbuf[1])[t];
    float4 s2 = ((const float4*)pbuf[2])[t];
    float4 s3 = ((const float4*)pbuf[3])[t];
    float4 sm = {s0.x+s1.x+s2.x+s3.x, s0.y+s1.y+s2.y+s3.y,
                 s0.z+s1.z+s2.z+s3.z, s0.w+s1.w+s2.w+s3.w};
    ushort4 u;
    u.x = f2bf(sm.x * inv); u.y = f2bf(sm.y * inv);
    u.z = f2bf(sm.z * inv); u.w = f2bf(sm.w * inv);
    ((ushort4*)pooled)[(size_t)b * 192 + t] = u;
  }
}

// ------------- K2: pack expert_w and gate_w1 into MFMA B-fragment layout ----
// frag tile = 16 cols x 32 k, entry [lane*8+e] = W[kt*32+(lane>>4)*8+e][nt*16+(lane&15)]
__global__ __launch_bounds__(256) void pack_kernel(
    const float* __restrict__ ew, const float* __restrict__ g1,
    unsigned short* __restrict__ Bpe, unsigned short* __restrict__ Bpg) {
  const int t = threadIdx.x, lane = t & 63;
  const int pair = blockIdx.x * 4 + (t >> 6);
  const int q = lane >> 4, j = lane & 15;
  const float* src; unsigned short* dst; int kt;
  if (pair < 2880) {                       // expert: 120 ntiles x 24 kt
    int nt = pair / 24; kt = pair % 24;
    int col = nt * 16 + j;
    src = ew + (size_t)(col / HIDn) * (En * HIDn) + (col % HIDn);
    dst = Bpe + (size_t)pair * 512;
  } else {                                 // gate: 9 heads x 24 ntiles x 24 kt
    int g = pair - 2880;
    int h = g / 576, rem = g % 576;
    int nt = rem / 24; kt = rem % 24;
    int col = nt * 16 + j;
    src = g1 + (size_t)h * (En * HIDn) + col;
    dst = Bpg + ((size_t)(h * 24 + nt) * 24 + kt) * 512;
  }
  unsigned short out[8] __attribute__((aligned(16)));
  #pragma unroll
  for (int e = 0; e < 8; ++e) {
    int k = kt * 32 + q * 8 + e;
    out[e] = f2bf(src[(size_t)k * HIDn]);
  }
  *(uint4*)&dst[lane * 8] = *(const uint4*)out;
}

// ------------- K2b: stable counting sort of samples by category ------------
__global__ __launch_bounds__(256) void sort_kernel(
    const int* __restrict__ category, int* __restrict__ rowsamp,
    int* __restrict__ posof, int* __restrict__ meta) {
  __shared__ int hist[NHn][256];
  __shared__ int padbase[NHn], total[NHn];
  __shared__ int tilecat_s[MAXTILES];
  __shared__ int padTiles_s;
  const int t = threadIdx.x;
  #pragma unroll
  for (int jj = 0; jj < NHn; ++jj) hist[jj][t] = 0;
  __syncthreads();
  for (int i = 0; i < 16; ++i) { int c = category[t * 16 + i]; hist[c][t]++; }
  __syncthreads();
  if (t < NHn) {                                  // scan each bin over threads
    int run = 0;
    for (int x = 0; x < 256; ++x) { int v = hist[t][x]; hist[t][x] = run; run += v; }
    total[t] = run;
  }
  __syncthreads();
  if (t == 0) {
    int pb = 0, mt = 0;
    for (int jj = 0; jj < NHn; ++jj) {
      padbase[jj] = pb;
      int nt = (total[jj] + 127) >> 7;
      for (int k2 = 0; k2 < nt; ++k2) { meta[1 + mt + k2] = jj; tilecat_s[mt + k2] = jj; }
      mt += nt; pb += nt << 7;
    }
    meta[0] = mt; padTiles_s = mt;
  }
  __syncthreads();
  const int padM = padTiles_s << 7;
  for (int mm = t; mm < padM; mm += 256) {        // default-fill padding rows
    int h = tilecat_s[mm >> 7];
    if (mm - padbase[h] >= total[h]) rowsamp[mm] = 0;
  }
  for (int i = 0; i < 16; ++i) {                  // stable scatter
    int idx = t * 16 + i; int c = category[idx];
    int off = hist[c][t]++;
    int pp = padbase[c] + off;
    rowsamp[pp] = idx;
    posof[idx] = pp;
  }
}

// ------------- K3a: Ce = relu(pooled @ expert_w + expert_b)  [4096 x 1920] --
__global__ __launch_bounds__(256) void gemme_kernel(
    const unsigned short* __restrict__ A, const unsigned short* __restrict__ Bpe,
    const float* __restrict__ eb, float* __restrict__ Ce) {
  __shared__ unsigned short Alds[128 * 40];
  __shared__ unsigned short Blds[8 * 512];
  const int t = threadIdx.x, lane = t & 63, wid = t >> 6;
  const int wm = wid >> 1, wn = wid & 1;
  const int m0 = blockIdx.y * 128, n0 = blockIdx.x * 128;
  const int ntg0 = blockIdx.x * 8;
  f32x4 acc[4][4] = {};
  const int r = t >> 2, c0 = (t & 3) * 8;
  for (int kt = 0; kt < 24; ++kt) {
    __syncthreads();
    *(uint4*)&Alds[r * 40 + c0] = *(const uint4*)&A[(size_t)(m0 + r) * En + kt * 32 + c0];
    *(uint4*)&Alds[(r + 64) * 40 + c0] = *(const uint4*)&A[(size_t)(m0 + r + 64) * En + kt * 32 + c0];
    #pragma unroll
    for (int rnd = 0; rnd < 2; ++rnd) {
      int chunk = t + rnd * 256;
      int nt = chunk >> 6, l2 = chunk & 63;
      *(uint4*)&Blds[nt * 512 + l2 * 8] =
          *(const uint4*)&Bpe[((size_t)(ntg0 + nt) * 24 + kt) * 512 + l2 * 8];
    }
    __syncthreads();
    short8 af[4], bfv[4];
    const int arow = wm * 64 + (lane & 15);
    const int aq = (lane >> 4) * 8;
    #pragma unroll
    for (int i = 0; i < 4; ++i) af[i] = *(const short8*)&Alds[(arow + i * 16) * 40 + aq];
    #pragma unroll
    for (int i = 0; i < 4; ++i) bfv[i] = *(const short8*)&Blds[(wn * 4 + i) * 512 + lane * 8];
    #pragma unroll
    for (int i = 0; i < 4; ++i)
      #pragma unroll
      for (int jj = 0; jj < 4; ++jj)
        acc[i][jj] = __builtin_amdgcn_mfma_f32_16x16x32_bf16(af[i], bfv[jj], acc[i][jj], 0, 0, 0);
  }
  const int rbase = m0 + wm * 64 + ((lane >> 4) << 2);
  const int cbase = n0 + wn * 64 + (lane & 15);
  #pragma unroll
  for (int i = 0; i < 4; ++i)
    #pragma unroll
    for (int jj = 0; jj < 4; ++jj) {
      int col = cbase + jj * 16;
      float bv = eb[col];
      #pragma unroll
      for (int rr = 0; rr < 4; ++rr) {
        float v = acc[i][jj][rr] + bv;
        Ce[(size_t)(rbase + i * 16 + rr) * NECOL + col] = v > 0.f ? v : 0.f;
      }
    }
}

// ------------- K3b: Cg = relu(pooled[perm] @ gate_w1[cat] + gate_b1[cat]) ---
__global__ __launch_bounds__(256) void gemmg_kernel(
    const unsigned short* __restrict__ A, const unsigned short* __restrict__ Bpg,
    const float* __restrict__ gb1, const int* __restrict__ rowsamp,
    const int* __restrict__ meta, float* __restrict__ Cg) {
  const int padTiles = meta[0];
  const int mt = blockIdx.y;
  if (mt >= padTiles) return;
  const int h = meta[1 + mt];
  __shared__ unsigned short Alds[128 * 40];
  __shared__ unsigned short Blds[8 * 512];
  __shared__ int rs[128];
  const int t = threadIdx.x, lane = t & 63, wid = t >> 6;
  const int wm = wid >> 1, wn = wid & 1;
  if (t < 128) rs[t] = rowsamp[mt * 128 + t];
  const int bx = blockIdx.x;
  f32x4 acc[4][4] = {};
  const int r = t >> 2, c0 = (t & 3) * 8;
  for (int kt = 0; kt < 24; ++kt) {
    __syncthreads();
    *(uint4*)&Alds[r * 40 + c0] = *(const uint4*)&A[(size_t)rs[r] * En + kt * 32 + c0];
    *(uint4*)&Alds[(r + 64) * 40 + c0] = *(const uint4*)&A[(size_t)rs[r + 64] * En + kt * 32 + c0];
    #pragma unroll
    for (int rnd = 0; rnd < 2; ++rnd) {
      int chunk = t + rnd * 256;
      int nt = chunk >> 6, l2 = chunk & 63;
      *(uint4*)&Blds[nt * 512 + l2 * 8] =
          *(const uint4*)&Bpg[((size_t)(h * 24 + bx * 8 + nt) * 24 + kt) * 512 + l2 * 8];
    }
    __syncthreads();
    short8 af[4], bfv[4];
    const int arow = wm * 64 + (lane & 15);
    const int aq = (lane >> 4) * 8;
    #pragma unroll
    for (int i = 0; i < 4; ++i) af[i] = *(const short8*)&Alds[(arow + i * 16) * 40 + aq];
    #pragma unroll
    for (int i = 0; i < 4; ++i) bfv[i] = *(const short8*)&Blds[(wn * 4 + i) * 512 + lane * 8];
    #pragma unroll
    for (int i = 0; i < 4; ++i)
      #pragma unroll
      for (int jj = 0; jj < 4; ++jj)
        acc[i][jj] = __builtin_amdgcn_mfma_f32_16x16x32_bf16(af[i], bfv[jj], acc[i][jj], 0, 0, 0);
  }
  const int rbase = mt * 128 + wm * 64 + ((lane >> 4) << 2);
  const int cbase = bx * 128 + wn * 64 + (lane & 15);
  #pragma unroll
  for (int i = 0; i < 4; ++i)
    #pragma unroll
    for (int jj = 0; jj < 4; ++jj) {
      int col = cbase + jj * 16;
      float bv = gb1[h * HIDn + col];
      #pragma unroll
      for (int rr = 0; rr < 4; ++rr) {
        float v = acc[i][jj][rr] + bv;
        Cg[(size_t)(rbase + i * 16 + rr) * HIDn + col] = v > 0.f ? v : 0.f;
      }
    }
}

// ------------- K4: per-sample gate softmax + expert combine + head ---------
__global__ __launch_bounds__(256) void tail_kernel(
    const float* __restrict__ Ce, const float* __restrict__ Cg,
    const int* __restrict__ posof, const int* __restrict__ category,
    const float* __restrict__ g2, const float* __restrict__ gb2,
    const float* __restrict__ hw, const float* __restrict__ hb,
    float* __restrict__ out) {
  const int lane = threadIdx.x & 63;
  const int b = blockIdx.x * 4 + (threadIdx.x >> 6);
  const int cat = category[b];
  const float* grow = Cg + (size_t)posof[b] * HIDn;
  const float* erow = Ce + (size_t)b * NECOL;
  float gh[6], hv[6];
  #pragma unroll
  for (int j = 0; j < 6; ++j) {
    int o = lane + 64 * j;
    gh[j] = grow[o];
    hv[j] = hw[cat * HIDn + o];
  }
  float g[5];
  #pragma unroll
  for (int k = 0; k < 5; ++k) {
    float p = 0.f;
    #pragma unroll
    for (int j = 0; j < 6; ++j) {
      int o = lane + 64 * j;
      p = fmaf(gh[j], g2[(size_t)(cat * HIDn + o) * 5 + k], p);
    }
    #pragma unroll
    for (int off = 32; off; off >>= 1) p += __shfl_xor(p, off);
    g[k] = p + gb2[cat * 5 + k];
  }
  float mx = g[0];
  #pragma unroll
  for (int k = 1; k < 5; ++k) mx = fmaxf(mx, g[k]);
  float gs = 0.f;
  #pragma unroll
  for (int k = 0; k < 5; ++k) { g[k] = __expf(g[k] - mx); gs += g[k]; }
  const float ginv = 1.f / gs;
  float sacc = 0.f;
  #pragma unroll
  for (int k = 0; k < 5; ++k) {
    float p = 0.f;
    #pragma unroll
    for (int j = 0; j < 6; ++j) {
      int o = lane + 64 * j;
      p = fmaf(erow[k * HIDn + o], hv[j], p);
    }
    sacc = fmaf(g[k] * ginv, p, sacc);
  }
  #pragma unroll
  for (int off = 32; off; off >>= 1) sacc += __shfl_xor(sacc, off);
  if (lane == 0) {
    float logit = sacc + hb[cat];
    out[b] = 1.f / (1.f + __expf(-logit));
  }
}

extern "C" void kernel_launch(void* const* d_in, const int* in_sizes, int n_in,
                              void* d_out, int out_size, void* d_ws, size_t ws_size,
                              hipStream_t stream) {
  const float* feature  = (const float*)d_in[0];
  const int*   masks    = (const int*)d_in[1];
  const int*   category = (const int*)d_in[2];
  const float* attn_w   = (const float*)d_in[3];
  // d_in[4] attn_b cancels in softmax
  const float* gate_w1  = (const float*)d_in[5];
  const float* gate_b1  = (const float*)d_in[6];
  const float* gate_w2  = (const float*)d_in[7];
  const float* gate_b2  = (const float*)d_in[8];
  const float* expert_w = (const float*)d_in[9];
  const float* expert_b = (const float*)d_in[10];
  const float* head_w   = (const float*)d_in[11];
  const float* head_b   = (const float*)d_in[12];
  float* out = (float*)d_out;

  char* ws = (char*)d_ws;
  unsigned short* pooled = (unsigned short*)(ws);             //  6,291,456 B
  unsigned short* Bpe    = (unsigned short*)(ws + 6291456);   //  2,949,120 B
  unsigned short* Bpg    = (unsigned short*)(ws + 9240576);   //  5,308,416 B
  float* Ce              = (float*)(ws + 14548992);           // 31,457,280 B
  float* Cg              = (float*)(ws + 46006272);           //  8,060,928 B
  int* rowsamp           = (int*)(ws + 54067200);             //     20,992 B
  int* posof             = (int*)(ws + 54088192);             //     16,384 B
  int* meta              = (int*)(ws + 54104576);             //        256 B

  pool_kernel<<<dim3(4096), dim3(256), 0, stream>>>(feature, masks, attn_w, pooled);
  pack_kernel<<<dim3(2016), dim3(256), 0, stream>>>(expert_w, gate_w1, Bpe, Bpg);
  sort_kernel<<<dim3(1), dim3(256), 0, stream>>>(category, rowsamp, posof, meta);
  gemme_kernel<<<dim3(15, 32), dim3(256), 0, stream>>>(pooled, Bpe, expert_b, Ce);
  gemmg_kernel<<<dim3(3, MAXTILES), dim3(256), 0, stream>>>(pooled, Bpg, gate_b1, rowsamp, meta, Cg);
  tail_kernel<<<dim3(1024), dim3(256), 0, stream>>>(Ce, Cg, posof, category,
                                                    gate_w2, gate_b2, head_w, head_b, out);
}